// Round 1
// baseline (524.122 us; speedup 1.0000x reference)
//
#include <hip/hip_runtime.h>

// CT-LSTM fused cell. B=1048576, INPUT=64, HIDDEN=16, D=80, 5 gates -> N=80.
// Strategy: z = [x|h] @ W + b via mfma_f32_16x16x32_bf16, one 16-row tile per
// wave per iteration, NO LDS: A-fragments are 8 contiguous floats per lane ->
// direct coalesced float4 global loads + cvt. W (25KB) register-resident as
// 15 B-fragments (3 K-steps x 5 gate tiles). Epilogue in fp32 on MFMA C/D
// layout (col=lane&15, row=quad*4+reg).

#define BATCH   1048576
#define NTILES  (BATCH / 16)      // 65536
#define L2E     1.442695041f
#define LN2     0.6931471806f

typedef __bf16 bf16x8 __attribute__((ext_vector_type(8)));
typedef float  f32x4  __attribute__((ext_vector_type(4)));

__device__ __forceinline__ float fast_tanh(float x) {
    // tanh(x) = 1 - 2/(e^{2x}+1); exact at +-inf, v_exp/v_rcp precision ~1ulp
    float e = __builtin_amdgcn_exp2f(x * (2.0f * L2E));
    return 1.0f - 2.0f * __builtin_amdgcn_rcpf(e + 1.0f);
}

__device__ __forceinline__ bf16x8 pack_bf16(float4 lo, float4 hi) {
    bf16x8 r;
    r[0] = (__bf16)lo.x; r[1] = (__bf16)lo.y; r[2] = (__bf16)lo.z; r[3] = (__bf16)lo.w;
    r[4] = (__bf16)hi.x; r[5] = (__bf16)hi.y; r[6] = (__bf16)hi.z; r[7] = (__bf16)hi.w;
    return r;
}

__global__ __launch_bounds__(256, 3)
void ctlstm_kernel(const float* __restrict__ x,
                   const float* __restrict__ hprev,
                   const float* __restrict__ cprev,
                   const float* __restrict__ dt,
                   const float* __restrict__ Wi, const float* __restrict__ bi,
                   const float* __restrict__ Wf, const float* __restrict__ bf_,
                   const float* __restrict__ Wo, const float* __restrict__ bo,
                   const float* __restrict__ Wc, const float* __restrict__ bc,
                   const float* __restrict__ Wd, const float* __restrict__ bd,
                   float* __restrict__ out)
{
    const int lane = threadIdx.x & 63;
    const int col  = lane & 15;   // MFMA n / C-col
    const int quad = lane >> 4;   // MFMA k-group / C-row-group

    const float* W[5]  = {Wi, Wf, Wo, Wc, Wd};
    const float* BP[5] = {bi, bf_, bo, bc, bd};

    // ---- B fragments (once per wave): B[k = kt*32 + quad*8 + j][n = col] ----
    bf16x8 Bfrag[3][5];
    float  biasv[5];
    #pragma unroll
    for (int t = 0; t < 5; ++t) {
        biasv[t] = BP[t][col];
        #pragma unroll
        for (int kt = 0; kt < 3; ++kt) {
            bf16x8 f;
            #pragma unroll
            for (int j = 0; j < 8; ++j) {
                int k = kt * 32 + quad * 8 + j;
                float v = (k < 80) ? W[t][k * 16 + col] : 0.0f;  // zero-pad K 80->96
                f[j] = (__bf16)v;
            }
            Bfrag[kt][t] = f;
        }
    }

    const int nwaves = (gridDim.x * blockDim.x) >> 6;
    const int gw     = (blockIdx.x * blockDim.x + threadIdx.x) >> 6;

    const float4* X4 = (const float4*)x;      // [B][16] float4 per row
    const float4* H4 = (const float4*)hprev;  // [B][4]  float4 per row

    for (int tile = gw; tile < NTILES; tile += nwaves) {
        const int rowbase = tile << 4;
        const int arow    = rowbase + col;    // A-fragment row for this lane

        // A-fragment loads: lane needs combined[arow][kt*32 + quad*8 .. +7]
        float4 a0 = X4[arow * 16 + quad * 2];          // k 0..31
        float4 a1 = X4[arow * 16 + quad * 2 + 1];
        float4 a2 = X4[arow * 16 + 8 + quad * 2];      // k 32..63
        float4 a3 = X4[arow * 16 + 8 + quad * 2 + 1];
        float4 a4 = make_float4(0.f, 0.f, 0.f, 0.f);   // k 64..95 (h_prev, pad)
        float4 a5 = make_float4(0.f, 0.f, 0.f, 0.f);
        if (quad < 2) {
            a4 = H4[arow * 4 + quad * 2];
            a5 = H4[arow * 4 + quad * 2 + 1];
        }
        bf16x8 A0 = pack_bf16(a0, a1);
        bf16x8 A1 = pack_bf16(a2, a3);
        bf16x8 A2 = pack_bf16(a4, a5);

        f32x4 acc[5];
        #pragma unroll
        for (int t = 0; t < 5; ++t) {
            f32x4 c0 = {biasv[t], biasv[t], biasv[t], biasv[t]};  // bias as C-init
            c0 = __builtin_amdgcn_mfma_f32_16x16x32_bf16(A0, Bfrag[0][t], c0, 0, 0, 0);
            c0 = __builtin_amdgcn_mfma_f32_16x16x32_bf16(A1, Bfrag[1][t], c0, 0, 0, 0);
            acc[t] = __builtin_amdgcn_mfma_f32_16x16x32_bf16(A2, Bfrag[2][t], c0, 0, 0, 0);
        }

        // ---- epilogue: lane owns (row = rowbase + quad*4 + r, col), r=0..3 ----
        #pragma unroll
        for (int r = 0; r < 4; ++r) {
            const int row = rowbase + quad * 4 + r;
            float cp  = cprev[row * 16 + col];
            float dtv = dt[row];

            float zi = acc[0][r], zf = acc[1][r], zo = acc[2][r];
            float zc = acc[3][r], zd = acc[4][r];

            float i_g = fast_tanh(zi);
            float f_g = fast_tanh(zf);
            float o_g = fast_tanh(zo);
            float ctl = fast_tanh(zc);

            // softplus(zd) = max(zd,0) + ln(1 + e^{-|zd|})
            float ax = fabsf(zd);
            float e  = __builtin_amdgcn_exp2f(-ax * L2E);
            float sp = fmaxf(zd, 0.0f) + __builtin_amdgcn_logf(1.0f + e) * LN2;

            float cdec = cp * __builtin_amdgcn_exp2f(-sp * dtv * L2E);
            float cn   = f_g * cdec + i_g * ctl;
            float hn   = o_g * fast_tanh(cn);

            out[row * 16 + col]              = hn;   // h_next
            out[BATCH * 16 + row * 16 + col] = cn;   // c_next
        }
    }
}

extern "C" void kernel_launch(void* const* d_in, const int* in_sizes, int n_in,
                              void* d_out, int out_size, void* d_ws, size_t ws_size,
                              hipStream_t stream) {
    const float* x  = (const float*)d_in[0];
    const float* h  = (const float*)d_in[1];
    const float* c  = (const float*)d_in[2];
    const float* dt = (const float*)d_in[3];
    // grid: 1024 blocks x 256 thr = 4096 waves -> 16 tiles/wave, even split
    ctlstm_kernel<<<1024, 256, 0, stream>>>(
        x, h, c, dt,
        (const float*)d_in[4],  (const float*)d_in[5],
        (const float*)d_in[6],  (const float*)d_in[7],
        (const float*)d_in[8],  (const float*)d_in[9],
        (const float*)d_in[10], (const float*)d_in[11],
        (const float*)d_in[12], (const float*)d_in[13],
        (float*)d_out);
}

// Round 2
// 510.107 us; speedup vs baseline: 1.0275x; 1.0275x over previous
//
#include <hip/hip_runtime.h>

// CT-LSTM fused cell. B=1048576, INPUT=64, HIDDEN=16, D=80, 5 gates -> N=80.
// R2: latency-bound fix. (1) Grid 1024->8192 blocks (2 tiles/wave) so ~28
// waves/CU can hide HBM latency. (2) W+bias pre-packed into bf16 MFMA B-frag
// layout in d_ws by a tiny setup kernel: per-wave setup drops from 120 scalar
// loads+cvts to 15 coalesced 16B loads. (3) Nontemporal output stores.

#define BATCH   1048576
#define NTILES  (BATCH / 16)      // 65536
#define L2E     1.442695041f
#define LN2     0.6931471806f

typedef __bf16 bf16x8 __attribute__((ext_vector_type(8)));
typedef float  f32x4  __attribute__((ext_vector_type(4)));

// d_ws layout: [15][64] bf16x8 fragments (chunk = t*3+kt, per-lane 16B),
// then float bias[5][16] at byte offset 15*64*16 = 15360.
#define WS_BIAS_OFF 15360

__device__ __forceinline__ float fast_tanh(float x) {
    float e = __builtin_amdgcn_exp2f(x * (2.0f * L2E));
    return 1.0f - 2.0f * __builtin_amdgcn_rcpf(e + 1.0f);
}

__global__ void pack_w_kernel(const float* __restrict__ Wi, const float* __restrict__ bi,
                              const float* __restrict__ Wf, const float* __restrict__ bf_,
                              const float* __restrict__ Wo, const float* __restrict__ bo,
                              const float* __restrict__ Wc, const float* __restrict__ bc,
                              const float* __restrict__ Wd, const float* __restrict__ bd,
                              void* __restrict__ ws)
{
    const float* W[5]  = {Wi, Wf, Wo, Wc, Wd};
    const float* BP[5] = {bi, bf_, bo, bc, bd};
    const int b    = blockIdx.x;      // 0..14 = W chunks, 15 = bias
    const int lane = threadIdx.x;     // 64 threads
    if (b < 15) {
        const int t = b / 3, kt = b % 3;
        const int quad = lane >> 4, col = lane & 15;
        bf16x8 f;
        #pragma unroll
        for (int j = 0; j < 8; ++j) {
            int k = kt * 32 + quad * 8 + j;
            float v = (k < 80) ? W[t][k * 16 + col] : 0.0f;  // zero-pad K 80->96
            f[j] = (__bf16)v;
        }
        ((bf16x8*)ws)[b * 64 + lane] = f;
    } else {
        if (lane < 80) {
            int t = lane >> 4, col = lane & 15;
            ((float*)((char*)ws + WS_BIAS_OFF))[lane] = BP[t][col];
        }
    }
}

__global__ __launch_bounds__(256, 4)
void ctlstm_kernel(const float* __restrict__ x,
                   const float* __restrict__ hprev,
                   const float* __restrict__ cprev,
                   const float* __restrict__ dt,
                   const void* __restrict__ ws,
                   float* __restrict__ out)
{
    const int lane = threadIdx.x & 63;
    const int col  = lane & 15;   // MFMA n / C-col
    const int quad = lane >> 4;   // MFMA k-group / C-row-group

    // ---- B fragments + bias: 15 coalesced 16B loads + 5 scalar (L2-hot) ----
    const bf16x8* wsfrag = (const bf16x8*)ws;
    const float*  wsbias = (const float*)((const char*)ws + WS_BIAS_OFF);
    bf16x8 Bfrag[3][5];
    float  biasv[5];
    #pragma unroll
    for (int t = 0; t < 5; ++t) {
        biasv[t] = wsbias[t * 16 + col];
        #pragma unroll
        for (int kt = 0; kt < 3; ++kt)
            Bfrag[kt][t] = wsfrag[(t * 3 + kt) * 64 + lane];
    }

    const int nwaves = (gridDim.x * blockDim.x) >> 6;
    const int gw     = (blockIdx.x * blockDim.x + threadIdx.x) >> 6;

    const float4* X4 = (const float4*)x;      // [B][16] float4 per row
    const float4* H4 = (const float4*)hprev;  // [B][4]  float4 per row

    for (int tile = gw; tile < NTILES; tile += nwaves) {
        const int rowbase = tile << 4;
        const int arow    = rowbase + col;    // A-fragment row for this lane

        // A-fragment loads: lane needs combined[arow][kt*32 + quad*8 .. +7]
        float4 a0 = X4[arow * 16 + quad * 2];          // k 0..31
        float4 a1 = X4[arow * 16 + quad * 2 + 1];
        float4 a2 = X4[arow * 16 + 8 + quad * 2];      // k 32..63
        float4 a3 = X4[arow * 16 + 8 + quad * 2 + 1];
        float4 a4 = make_float4(0.f, 0.f, 0.f, 0.f);   // k 64..95 (h_prev, pad)
        float4 a5 = make_float4(0.f, 0.f, 0.f, 0.f);
        if (quad < 2) {
            a4 = H4[arow * 4 + quad * 2];
            a5 = H4[arow * 4 + quad * 2 + 1];
        }

        // Epilogue operand prefetch (independent of MFMA chain)
        float cp[4], dtv[4];
        #pragma unroll
        for (int r = 0; r < 4; ++r) {
            const int row = rowbase + quad * 4 + r;
            cp[r]  = cprev[row * 16 + col];
            dtv[r] = dt[row];
        }

        bf16x8 A0, A1, A2;
        #pragma unroll
        for (int j = 0; j < 4; ++j) {
            A0[j]     = (__bf16)((const float*)&a0)[j];
            A0[j + 4] = (__bf16)((const float*)&a1)[j];
            A1[j]     = (__bf16)((const float*)&a2)[j];
            A1[j + 4] = (__bf16)((const float*)&a3)[j];
            A2[j]     = (__bf16)((const float*)&a4)[j];
            A2[j + 4] = (__bf16)((const float*)&a5)[j];
        }

        f32x4 acc[5];
        #pragma unroll
        for (int t = 0; t < 5; ++t) {
            f32x4 c0 = {biasv[t], biasv[t], biasv[t], biasv[t]};  // bias as C-init
            c0 = __builtin_amdgcn_mfma_f32_16x16x32_bf16(A0, Bfrag[0][t], c0, 0, 0, 0);
            c0 = __builtin_amdgcn_mfma_f32_16x16x32_bf16(A1, Bfrag[1][t], c0, 0, 0, 0);
            acc[t] = __builtin_amdgcn_mfma_f32_16x16x32_bf16(A2, Bfrag[2][t], c0, 0, 0, 0);
        }

        // ---- epilogue: lane owns (row = rowbase + quad*4 + r, col), r=0..3 ----
        #pragma unroll
        for (int r = 0; r < 4; ++r) {
            const int row = rowbase + quad * 4 + r;

            float zi = acc[0][r], zf = acc[1][r], zo = acc[2][r];
            float zc = acc[3][r], zd = acc[4][r];

            float i_g = fast_tanh(zi);
            float f_g = fast_tanh(zf);
            float o_g = fast_tanh(zo);
            float ctl = fast_tanh(zc);

            // softplus(zd) = max(zd,0) + ln(1 + e^{-|zd|})
            float ax = fabsf(zd);
            float e  = __builtin_amdgcn_exp2f(-ax * L2E);
            float sp = fmaxf(zd, 0.0f) + __builtin_amdgcn_logf(1.0f + e) * LN2;

            float cdec = cp[r] * __builtin_amdgcn_exp2f(-sp * dtv[r] * L2E);
            float cn   = f_g * cdec + i_g * ctl;
            float hn   = o_g * fast_tanh(cn);

            __builtin_nontemporal_store(hn, &out[row * 16 + col]);               // h_next
            __builtin_nontemporal_store(cn, &out[BATCH * 16 + row * 16 + col]);  // c_next
        }
    }
}

extern "C" void kernel_launch(void* const* d_in, const int* in_sizes, int n_in,
                              void* d_out, int out_size, void* d_ws, size_t ws_size,
                              hipStream_t stream) {
    pack_w_kernel<<<16, 64, 0, stream>>>(
        (const float*)d_in[4],  (const float*)d_in[5],
        (const float*)d_in[6],  (const float*)d_in[7],
        (const float*)d_in[8],  (const float*)d_in[9],
        (const float*)d_in[10], (const float*)d_in[11],
        (const float*)d_in[12], (const float*)d_in[13],
        d_ws);
    // 8192 blocks x 256 thr = 32768 waves -> 2 tiles/wave
    ctlstm_kernel<<<8192, 256, 0, stream>>>(
        (const float*)d_in[0], (const float*)d_in[1],
        (const float*)d_in[2], (const float*)d_in[3],
        d_ws, (float*)d_out);
}